// Round 8
// baseline (334.931 us; speedup 1.0000x reference)
//
#include <hip/hip_runtime.h>
#include <stdint.h>

typedef float f32x4 __attribute__((ext_vector_type(4)));

#define NROWS 8192
#define DIM   1024
#define BK    128
#define NKT   (DIM / BK)   // 8
#define MARGIN 0.3f

// async global->LDS, 16B per lane; LDS dest = wave-uniform base + lane*16
#define GLOAD_LDS16(gp, lp)                                                    \
  __builtin_amdgcn_global_load_lds(                                            \
      (const __attribute__((address_space(1))) void*)(gp),                     \
      (__attribute__((address_space(3))) void*)(lp), 16, 0, 0)

// fp32 [8192*1024] -> fp8 e4m3 (OCP, v_cvt_pk_fp8_f32); 16 elems/thread.
// Also zeroes the scalar output.  (verified correct R6/R7: absmax 0.0)
__global__ __launch_bounds__(256) void cvt_f32_fp8(const float* __restrict__ in,
                                                   uint8_t* __restrict__ out,
                                                   float* __restrict__ loss) {
  if (blockIdx.x == 0 && threadIdx.x == 0) loss[0] = 0.0f;
  size_t i = ((size_t)blockIdx.x * 256 + threadIdx.x) * 16;
  float4 v0 = *(const float4*)(in + i);
  float4 v1 = *(const float4*)(in + i + 4);
  float4 v2 = *(const float4*)(in + i + 8);
  float4 v3 = *(const float4*)(in + i + 12);
  int w0 = 0, w1 = 0, w2 = 0, w3 = 0;
  w0 = __builtin_amdgcn_cvt_pk_fp8_f32(v0.x, v0.y, w0, false);
  w0 = __builtin_amdgcn_cvt_pk_fp8_f32(v0.z, v0.w, w0, true);
  w1 = __builtin_amdgcn_cvt_pk_fp8_f32(v1.x, v1.y, w1, false);
  w1 = __builtin_amdgcn_cvt_pk_fp8_f32(v1.z, v1.w, w1, true);
  w2 = __builtin_amdgcn_cvt_pk_fp8_f32(v2.x, v2.y, w2, false);
  w2 = __builtin_amdgcn_cvt_pk_fp8_f32(v2.z, v2.w, w2, true);
  w3 = __builtin_amdgcn_cvt_pk_fp8_f32(v3.x, v3.y, w3, false);
  w3 = __builtin_amdgcn_cvt_pk_fp8_f32(v3.z, v3.w, w3, true);
  uint4 p; p.x = (unsigned)w0; p.y = (unsigned)w1; p.z = (unsigned)w2; p.w = (unsigned)w3;
  *(uint4*)(out + i) = p;
}

// One block = one 128x128 tile of sim = A*A^T (upper triangle, bi<=bj).
// fp8 e4m3 via NON-scaled mfma_f32_16x16x32_fp8_fp8: 2-reg A/B operands
// (8 B/lane) keep register pressure in R4's clean budget class (R6/R7's
// mfma_scale v8i operands caused allocator spills -> 97-905 MB scratch).
// BK=128: 8 K-iterations (half of R4's 16 barrier-drain events), half the
// staged bytes, MFMA rate unchanged (fp8 16x16x32 == bf16 rate, m11).
__global__ __launch_bounds__(256, 3) void gram_loss(const uint8_t* __restrict__ A8,
                                                    const int* __restrict__ targets,
                                                    float* __restrict__ out) {
  __shared__ uint8_t As[128 * 128];   // 16 KB, plain row-major [128][128]
  __shared__ uint8_t Bs[128 * 128];   // 16 KB
  __shared__ int tRow[128];
  __shared__ int tCol[128];
  __shared__ float wsum[4];

  // linear block id -> (bi, bj) with 0 <= bi <= bj < 64  (fp32 guess + exact fixup)
  int t = blockIdx.x;
  int bi = (int)(0.5f * (129.0f - __builtin_sqrtf(129.0f * 129.0f - 8.0f * (float)t)));
  if (bi < 0) bi = 0;
  if (bi > 63) bi = 63;
  while (bi < 63 && ((bi + 1) * (129 - (bi + 1))) / 2 <= t) ++bi;
  while (bi > 0 && (bi * (129 - bi)) / 2 > t) --bi;
  int bj = bi + (t - (bi * (129 - bi)) / 2);

  const int iBase = bi * 128;
  const int jBase = bj * 128;

  const int tid  = threadIdx.x;
  const int wave = tid >> 6;
  const int lane = tid & 63;

  if (tid < 128) tRow[tid] = targets[iBase + tid];
  else           tCol[tid - 128] = targets[jBase + tid - 128];

  // staging: wave w stages rows [w*32, w*32+32) of both tiles, 4 loads each.
  // one load = 64 lanes x 16B = 8 rows x 128B; lane -> row offset lane>>3,
  // byte-col (lane&7)*16 (contiguous).
  const int lrow = lane >> 3;                 // 0..7
  const int cg   = lane & 7;                  // col-group (x16B)
  const uint8_t* gA = A8 + (size_t)(iBase + wave * 32 + lrow) * DIM + cg * 16;
  const uint8_t* gB = A8 + (size_t)(jBase + wave * 32 + lrow) * DIM + cg * 16;
  uint8_t* lA = &As[wave * 32 * 128];
  uint8_t* lB = &Bs[wave * 32 * 128];

  const int m0 = (wave >> 1) * 64;
  const int n0 = (wave & 1) * 64;
  const int fr = lane & 15;    // row within 16-block
  const int h  = lane >> 4;    // 0..3: k-subgroup (8 bytes) within 32B k-step

  f32x4 acc[4][4] = {};

  for (int kt = 0; kt < NKT; ++kt) {
    __syncthreads();  // previous tile fully consumed
    const int kOff = kt * BK;
#pragma unroll
    for (int l = 0; l < 4; ++l)
      GLOAD_LDS16(gA + (size_t)(l * 8) * DIM + kOff, lA + l * 8 * 128);
#pragma unroll
    for (int l = 0; l < 4; ++l)
      GLOAD_LDS16(gB + (size_t)(l * 8) * DIM + kOff, lB + l * 8 * 128);
    __syncthreads();  // vmcnt(0) drain + barrier: tile landed

    // 4 k-steps of 32; per step each lane reads 8B of A and B per tile-row
    // (fragment: row = base+fr, k-bytes = ks*32 + h*8 .. +8)
#pragma unroll
    for (int ks = 0; ks < 4; ++ks) {
      long af[4], bf[4];
#pragma unroll
      for (int mi = 0; mi < 4; ++mi)
        af[mi] = *(const long*)&As[(m0 + mi * 16 + fr) * 128 + ks * 32 + h * 8];
#pragma unroll
      for (int ni = 0; ni < 4; ++ni)
        bf[ni] = *(const long*)&Bs[(n0 + ni * 16 + fr) * 128 + ks * 32 + h * 8];
#pragma unroll
      for (int mi = 0; mi < 4; ++mi)
#pragma unroll
        for (int ni = 0; ni < 4; ++ni)
          acc[mi][ni] = __builtin_amdgcn_mfma_f32_16x16x32_fp8_fp8(
              af[mi], bf[ni], acc[mi][ni], 0, 0, 0);
    }
  }

  // epilogue: C/D layout col = lane&15, row = (lane>>4)*4 + reg (dtype-indep)
  const int col = lane & 15;
  const int rquad = (lane >> 4) * 4;
  float lsum = 0.0f;
#pragma unroll
  for (int ni = 0; ni < 4; ++ni) {
    const int tj = tCol[n0 + ni * 16 + col];
#pragma unroll
    for (int mi = 0; mi < 4; ++mi) {
#pragma unroll
      for (int r = 0; r < 4; ++r) {
        float s = acc[mi][ni][r];
        int ti = tRow[m0 + mi * 16 + rquad + r];
        lsum += (ti == tj) ? (s < 1.0f ? 1.0f - s : 0.0f)
                           : (s > MARGIN ? s : 0.0f);
      }
    }
  }
  if (bi != bj) lsum *= 2.0f;  // symmetric half counted twice

#pragma unroll
  for (int off = 32; off > 0; off >>= 1) lsum += __shfl_down(lsum, off, 64);
  if (lane == 0) wsum[wave] = lsum;
  __syncthreads();
  if (tid == 0)
    atomicAdd(out, (wsum[0] + wsum[1] + wsum[2] + wsum[3]) * (1.0f / (float)NROWS));
}

extern "C" void kernel_launch(void* const* d_in, const int* in_sizes, int n_in,
                              void* d_out, int out_size, void* d_ws, size_t ws_size,
                              hipStream_t stream) {
  const float* x = (const float*)d_in[0];
  const int* targets = (const int*)d_in[1];
  float* out = (float*)d_out;
  uint8_t* x8 = (uint8_t*)d_ws;  // 8192*1024 = 8 MiB scratch

  cvt_f32_fp8<<<2048, 256, 0, stream>>>(x, x8, out);   // 8388608 = 2048*256*16
  gram_loss<<<2080, 256, 0, stream>>>(x8, targets, out);  // 64*65/2 upper-tri blocks
}

// Round 9
// 136.426 us; speedup vs baseline: 2.4550x; 2.4550x over previous
//
#include <hip/hip_runtime.h>
#include <stdint.h>

typedef float f32x4 __attribute__((ext_vector_type(4)));

#define NROWS 8192
#define DIM   1024
#define BK    128
#define NKT   (DIM / BK)   // 8
#define MARGIN 0.3f

// async global->LDS, 16B per lane; LDS dest = wave-uniform base + lane*16
#define GLOAD_LDS16(gp, lp)                                                    \
  __builtin_amdgcn_global_load_lds(                                            \
      (const __attribute__((address_space(1))) void*)(gp),                     \
      (__attribute__((address_space(3))) void*)(lp), 16, 0, 0)

// fp32 [8192*1024] -> fp8 e4m3 (OCP, v_cvt_pk_fp8_f32); 16 elems/thread.
// Also zeroes the scalar output.  (verified correct R6-R8: absmax 0.0)
__global__ __launch_bounds__(256) void cvt_f32_fp8(const float* __restrict__ in,
                                                   uint8_t* __restrict__ out,
                                                   float* __restrict__ loss) {
  if (blockIdx.x == 0 && threadIdx.x == 0) loss[0] = 0.0f;
  size_t i = ((size_t)blockIdx.x * 256 + threadIdx.x) * 16;
  float4 v0 = *(const float4*)(in + i);
  float4 v1 = *(const float4*)(in + i + 4);
  float4 v2 = *(const float4*)(in + i + 8);
  float4 v3 = *(const float4*)(in + i + 12);
  int w0 = 0, w1 = 0, w2 = 0, w3 = 0;
  w0 = __builtin_amdgcn_cvt_pk_fp8_f32(v0.x, v0.y, w0, false);
  w0 = __builtin_amdgcn_cvt_pk_fp8_f32(v0.z, v0.w, w0, true);
  w1 = __builtin_amdgcn_cvt_pk_fp8_f32(v1.x, v1.y, w1, false);
  w1 = __builtin_amdgcn_cvt_pk_fp8_f32(v1.z, v1.w, w1, true);
  w2 = __builtin_amdgcn_cvt_pk_fp8_f32(v2.x, v2.y, w2, false);
  w2 = __builtin_amdgcn_cvt_pk_fp8_f32(v2.z, v2.w, w2, true);
  w3 = __builtin_amdgcn_cvt_pk_fp8_f32(v3.x, v3.y, w3, false);
  w3 = __builtin_amdgcn_cvt_pk_fp8_f32(v3.z, v3.w, w3, true);
  uint4 p; p.x = (unsigned)w0; p.y = (unsigned)w1; p.z = (unsigned)w2; p.w = (unsigned)w3;
  *(uint4*)(out + i) = p;
}

// One block = one 128x128 tile of sim = A*A^T (upper triangle, bi<=bj).
// fp8 e4m3, non-scaled mfma_f32_16x16x32_fp8_fp8 (2-reg operands, no spill).
// R9: XOR-swizzled LDS. R8's plain [128][128B] layout has row stride = full
// bank wrap -> fragment read bank = f(k-offset) only, fr drops out => real
// 16-way conflict (measured 60 extra cyc per ds_read_b64). Swizzle: LDS row
// r, 16B-slot s holds global col-group s ^ (r&7); applied on the GLOBAL
// source address (global_load_lds pins slot = lane*16B). Reader uses the
// same mapping -> each bank-pair serves 4 lanes over 4 phases = conflict-free.
__global__ __launch_bounds__(256, 3) void gram_loss(const uint8_t* __restrict__ A8,
                                                    const int* __restrict__ targets,
                                                    float* __restrict__ out) {
  __shared__ uint8_t As[128 * 128];   // 16 KB, swizzled [128][8 slots of 16B]
  __shared__ uint8_t Bs[128 * 128];   // 16 KB
  __shared__ int tRow[128];
  __shared__ int tCol[128];
  __shared__ float wsum[4];

  // linear block id -> (bi, bj) with 0 <= bi <= bj < 64  (fp32 guess + exact fixup)
  int t = blockIdx.x;
  int bi = (int)(0.5f * (129.0f - __builtin_sqrtf(129.0f * 129.0f - 8.0f * (float)t)));
  if (bi < 0) bi = 0;
  if (bi > 63) bi = 63;
  while (bi < 63 && ((bi + 1) * (129 - (bi + 1))) / 2 <= t) ++bi;
  while (bi > 0 && (bi * (129 - bi)) / 2 > t) --bi;
  int bj = bi + (t - (bi * (129 - bi)) / 2);

  const int iBase = bi * 128;
  const int jBase = bj * 128;

  const int tid  = threadIdx.x;
  const int wave = tid >> 6;
  const int lane = tid & 63;

  if (tid < 128) tRow[tid] = targets[iBase + tid];
  else           tCol[tid - 128] = targets[jBase + tid - 128];

  // staging: wave w stages rows [w*32, w*32+32) of both tiles, 4 loads each.
  // one load = 64 lanes x 16B = 8 rows x 128B; lane -> row offset lane>>3,
  // SWIZZLED source col-group (lane&7) ^ (lane>>3)  [row&7 == lane>>3 here
  // since each load covers an 8-row-aligned group].
  const int lrow = lane >> 3;                 // 0..7 == row&7
  const int cg   = (lane & 7) ^ lrow;         // swizzled source col-group
  const uint8_t* gA = A8 + (size_t)(iBase + wave * 32 + lrow) * DIM + cg * 16;
  const uint8_t* gB = A8 + (size_t)(jBase + wave * 32 + lrow) * DIM + cg * 16;
  uint8_t* lA = &As[wave * 32 * 128];
  uint8_t* lB = &Bs[wave * 32 * 128];

  const int m0 = (wave >> 1) * 64;
  const int n0 = (wave & 1) * 64;
  const int fr = lane & 15;    // row within 16-block
  const int h  = lane >> 4;    // 0..3: k-subgroup (8 bytes) within 32B k-step
  const int r7 = fr & 7;       // swizzle key (rows are 16-aligned per frag)
  const int hHi = h >> 1;      // which 16B group inside the 32B k-step
  const int hLo = (h & 1) * 8; // byte offset inside the 16B group

  f32x4 acc[4][4] = {};

  for (int kt = 0; kt < NKT; ++kt) {
    __syncthreads();  // previous tile fully consumed
    const int kOff = kt * BK;
#pragma unroll
    for (int l = 0; l < 4; ++l)
      GLOAD_LDS16(gA + (size_t)(l * 8) * DIM + kOff, lA + l * 8 * 128);
#pragma unroll
    for (int l = 0; l < 4; ++l)
      GLOAD_LDS16(gB + (size_t)(l * 8) * DIM + kOff, lB + l * 8 * 128);
    __syncthreads();  // vmcnt(0) drain + barrier: tile landed

    // 4 k-steps of 32; lane reads 8B of A/B per tile-row from swizzled slot
#pragma unroll
    for (int ks = 0; ks < 4; ++ks) {
      const int colOff = (((ks * 2 + hHi) ^ r7) * 16) + hLo;
      long af[4], bf[4];
#pragma unroll
      for (int mi = 0; mi < 4; ++mi)
        af[mi] = *(const long*)&As[(m0 + mi * 16 + fr) * 128 + colOff];
#pragma unroll
      for (int ni = 0; ni < 4; ++ni)
        bf[ni] = *(const long*)&Bs[(n0 + ni * 16 + fr) * 128 + colOff];
#pragma unroll
      for (int mi = 0; mi < 4; ++mi)
#pragma unroll
        for (int ni = 0; ni < 4; ++ni)
          acc[mi][ni] = __builtin_amdgcn_mfma_f32_16x16x32_fp8_fp8(
              af[mi], bf[ni], acc[mi][ni], 0, 0, 0);
    }
  }

  // epilogue: C/D layout col = lane&15, row = (lane>>4)*4 + reg (dtype-indep)
  const int col = lane & 15;
  const int rquad = (lane >> 4) * 4;
  float lsum = 0.0f;
#pragma unroll
  for (int ni = 0; ni < 4; ++ni) {
    const int tj = tCol[n0 + ni * 16 + col];
#pragma unroll
    for (int mi = 0; mi < 4; ++mi) {
#pragma unroll
      for (int r = 0; r < 4; ++r) {
        float s = acc[mi][ni][r];
        int ti = tRow[m0 + mi * 16 + rquad + r];
        lsum += (ti == tj) ? (s < 1.0f ? 1.0f - s : 0.0f)
                           : (s > MARGIN ? s : 0.0f);
      }
    }
  }
  if (bi != bj) lsum *= 2.0f;  // symmetric half counted twice

#pragma unroll
  for (int off = 32; off > 0; off >>= 1) lsum += __shfl_down(lsum, off, 64);
  if (lane == 0) wsum[wave] = lsum;
  __syncthreads();
  if (tid == 0)
    atomicAdd(out, (wsum[0] + wsum[1] + wsum[2] + wsum[3]) * (1.0f / (float)NROWS));
}

extern "C" void kernel_launch(void* const* d_in, const int* in_sizes, int n_in,
                              void* d_out, int out_size, void* d_ws, size_t ws_size,
                              hipStream_t stream) {
  const float* x = (const float*)d_in[0];
  const int* targets = (const int*)d_in[1];
  float* out = (float*)d_out;
  uint8_t* x8 = (uint8_t*)d_ws;  // 8192*1024 = 8 MiB scratch

  cvt_f32_fp8<<<2048, 256, 0, stream>>>(x, x8, out);   // 8388608 = 2048*256*16
  gram_loss<<<2080, 256, 0, stream>>>(x8, targets, out);  // 64*65/2 upper-tri blocks
}